// Round 2
// baseline (3530.433 us; speedup 1.0000x reference)
//
#include <hip/hip_runtime.h>

#define HDIM 2048
#define TSTEPS 1024
#define NBLK 256
#define NTHR 256

typedef unsigned long long ull;

// ---------------------------------------------------------------------------
// Init: snake-order x, zero+tag the h slot buffers.
// slot = (tag<<32) | f32bits.  s0 holds h_0 = 0 with tag 0.
// ---------------------------------------------------------------------------
__global__ void prep_init(const float* __restrict__ x,
                          float* __restrict__ xs,
                          ull* __restrict__ s0, ull* __restrict__ s1) {
    int i = blockIdx.x * blockDim.x + threadIdx.x;   // 2048 threads
    if (i < HDIM) {
        s0[i] = 0ULL;                       // tag 0, value 0.0f
        s1[i] = 0xFFFFFFFF00000000ULL;      // tag -1 (never matched)
    }
    if (i < TSTEPS) {
        int y = i >> 5, xx = i & 31;
        int src = (y & 1) ? (y * 32 + (31 - xx)) : (y * 32 + xx);
        xs[i] = x[src];
    }
}

// ---------------------------------------------------------------------------
// Rank-1 precompute: ve_g = We @ Wg, cb_g = be @ Wg + b_g  (g = r,z,n)
// grid 96 = 3 gates x 32 col-groups of 64; block 256 = 64 cols x 4 row chunks
// ---------------------------------------------------------------------------
__global__ void prep_ve(const float* __restrict__ We,
                        const float* __restrict__ be,
                        const float* __restrict__ Wir,
                        const float* __restrict__ bir,
                        const float* __restrict__ Wiz,
                        const float* __restrict__ biz,
                        const float* __restrict__ Win,
                        const float* __restrict__ bin_,
                        float* __restrict__ ve, float* __restrict__ cb) {
    int gate = blockIdx.x >> 5;
    int cg   = blockIdx.x & 31;
    int tid  = threadIdx.x;
    int colL = tid & 63;
    int chunk = tid >> 6;
    int col  = cg * 64 + colL;
    const float* Wg = (gate == 0) ? Wir : (gate == 1) ? Wiz : Win;
    const float* bg = (gate == 0) ? bir : (gate == 1) ? biz : bin_;
    float accE = 0.f, accB = 0.f;
    int i0 = chunk * 512;
    for (int i = i0; i < i0 + 512; ++i) {
        float w = Wg[(size_t)i * HDIM + col];
        accE = fmaf(We[i], w, accE);
        accB = fmaf(be[i], w, accB);
    }
    __shared__ float sE[4][64], sB[4][64];
    sE[chunk][colL] = accE; sB[chunk][colL] = accB;
    __syncthreads();
    if (chunk == 0) {
        float e = sE[0][colL] + sE[1][colL] + sE[2][colL] + sE[3][colL];
        float b = sB[0][colL] + sB[1][colL] + sB[2][colL] + sB[3][colL];
        ve[gate * HDIM + col] = e;
        cb[gate * HDIM + col] = b + bg[col];
    }
}

// ---------------------------------------------------------------------------
// Persistent sequential GRU. 256 blocks (1/CU) x 256 threads.
// Thread (c = tid&7, r = tid>>3): column col = blk*8+c, rows [r*64, r*64+64).
// Weights held in 192 VGPRs per thread for the whole kernel.
// Cross-block sync: tagged 8B atomic slots, 2 buffers, no fences needed.
// ---------------------------------------------------------------------------
__global__ __launch_bounds__(NTHR, 1) void gru_seq(
    const float* __restrict__ Whr,
    const float* __restrict__ Whz,
    const float* __restrict__ Whn,
    const float* __restrict__ bhn,
    const float* __restrict__ xs,
    const float* __restrict__ ve,
    const float* __restrict__ cb,
    ull* __restrict__ s0, ull* __restrict__ s1) {
    const int tid = threadIdx.x;
    const int blk = blockIdx.x;
    const int c = tid & 7;
    const int r = tid >> 3;          // 0..31
    const int col = blk * 8 + c;
    const int row0 = r * 64;

    __shared__ float lds_h[HDIM + (HDIM >> 6) * 4];  // +4 dwords pad per 64
    __shared__ float part[4][3][8];

    // --- load this thread's weight slice into registers (one-time) ---
    float wr[64], wz[64], wn[64];
    {
        const float* p0 = Whr + (size_t)row0 * HDIM + col;
        const float* p1 = Whz + (size_t)row0 * HDIM + col;
        const float* p2 = Whn + (size_t)row0 * HDIM + col;
#pragma unroll
        for (int k = 0; k < 64; ++k) {
            wr[k] = p0[(size_t)k * HDIM];
            wz[k] = p1[(size_t)k * HDIM];
            wn[k] = p2[(size_t)k * HDIM];
        }
    }

    // --- per-column constants (only lanes 0..7 finalize) ---
    float vrc = 0, vzc = 0, vnc = 0, crc = 0, czc = 0, cnc = 0, bhc = 0;
    if (tid < 8) {
        int j = blk * 8 + tid;
        vrc = ve[j];          vzc = ve[HDIM + j];  vnc = ve[2 * HDIM + j];
        crc = cb[j];          czc = cb[HDIM + j];  cnc = cb[2 * HDIM + j];
        bhc = bhn[j];
    }

    const int sbase = tid * 8;                    // this thread's 8 h slots
    const int lbase = row0 + ((row0 >> 6) << 2);  // padded LDS base = r*68

    for (int t = 0; t < TSTEPS; ++t) {
        ull* sin  = (t & 1) ? s1 : s0;
        ull* sout = (t & 1) ? s0 : s1;

        // ---- stage h_t: poll tagged slots, write to LDS ----
        {
            ull v[8];
            for (;;) {
#pragma unroll
                for (int k = 0; k < 8; ++k)
                    v[k] = __hip_atomic_load(&sin[sbase + k], __ATOMIC_RELAXED,
                                             __HIP_MEMORY_SCOPE_AGENT);
                int ok = 1;
#pragma unroll
                for (int k = 0; k < 8; ++k) ok &= ((int)(v[k] >> 32) == t);
                if (ok) break;
            }
#pragma unroll
            for (int k = 0; k < 8; ++k) {
                int i = sbase + k;
                lds_h[i + ((i >> 6) << 2)] = __uint_as_float((unsigned int)v[k]);
            }
        }
        __syncthreads();

        // ---- partial dots from register-resident weights ----
        float a0 = 0.f, a1 = 0.f, a2 = 0.f;
#pragma unroll
        for (int k = 0; k < 64; ++k) {
            float hv = lds_h[lbase + k];
            a0 = fmaf(hv, wr[k], a0);
            a1 = fmaf(hv, wz[k], a1);
            a2 = fmaf(hv, wn[k], a2);
        }
        // reduce across the 8 row-groups within the wave (lane bits 3,4,5)
#pragma unroll
        for (int m = 8; m < 64; m <<= 1) {
            a0 += __shfl_xor(a0, m, 64);
            a1 += __shfl_xor(a1, m, 64);
            a2 += __shfl_xor(a2, m, 64);
        }
        const int lane = tid & 63, wv = tid >> 6;
        if ((lane >> 3) == 0) {
            part[wv][0][lane] = a0;
            part[wv][1][lane] = a1;
            part[wv][2][lane] = a2;
        }
        __syncthreads();

        // ---- finalize 8 columns, store tagged h_{t+1} ----
        if (tid < 8) {
            float Sr = part[0][0][tid] + part[1][0][tid] + part[2][0][tid] + part[3][0][tid];
            float Sz = part[0][1][tid] + part[1][1][tid] + part[2][1][tid] + part[3][1][tid];
            float Sn = part[0][2][tid] + part[1][2][tid] + part[2][2][tid] + part[3][2][tid];
            float xt = xs[t];
            float arv = fmaf(xt, vrc, crc) + Sr;
            float azv = fmaf(xt, vzc, czc) + Sz;
            float anv = fmaf(xt, vnc, cnc);
            float rg = 1.f / (1.f + __expf(-arv));
            float zg = 1.f / (1.f + __expf(-azv));
            float ng = tanhf(anv + rg * (Sn + bhc));
            int j = col;  // tid<8 => c==tid
            float hold = lds_h[j + ((j >> 6) << 2)];
            float hnew = (1.f - zg) * ng + zg * hold;
            ull pkt = ((ull)(unsigned int)(t + 1) << 32) | (ull)__float_as_uint(hnew);
            __hip_atomic_store(&sout[j], pkt, __ATOMIC_RELAXED,
                               __HIP_MEMORY_SCOPE_AGENT);
        }
        __syncthreads();  // protect lds_h/part before next iteration's stage
    }
}

// ---------------------------------------------------------------------------
__global__ void finalize(const ull* __restrict__ s0,
                         float* __restrict__ out) {
    int i = blockIdx.x * blockDim.x + threadIdx.x;
    if (i < HDIM) out[i] = __uint_as_float((unsigned int)s0[i]);
}

extern "C" void kernel_launch(void* const* d_in, const int* in_sizes, int n_in,
                              void* d_out, int out_size, void* d_ws, size_t ws_size,
                              hipStream_t stream) {
    const float* x    = (const float*)d_in[0];
    const float* We   = (const float*)d_in[1];
    const float* be   = (const float*)d_in[2];
    const float* Wir  = (const float*)d_in[3];
    const float* bir  = (const float*)d_in[4];
    const float* Wiz  = (const float*)d_in[5];
    const float* biz  = (const float*)d_in[6];
    const float* Win  = (const float*)d_in[7];
    const float* bin_ = (const float*)d_in[8];
    const float* Whr  = (const float*)d_in[9];
    const float* Whz  = (const float*)d_in[10];
    const float* Whn  = (const float*)d_in[11];
    const float* bhn  = (const float*)d_in[12];

    float* W  = (float*)d_ws;
    float* xs = W;                         // 1024 f32
    float* ve = W + 1024;                  // 3*2048 f32
    float* cb = W + 1024 + 3 * HDIM;       // 3*2048 f32
    ull*   s0 = (ull*)(W + 1024 + 6 * HDIM);  // byte 53248, 8B aligned
    ull*   s1 = s0 + HDIM;

    prep_init<<<8, 256, 0, stream>>>(x, xs, s0, s1);
    prep_ve<<<96, 256, 0, stream>>>(We, be, Wir, bir, Wiz, biz, Win, bin_, ve, cb);
    gru_seq<<<NBLK, NTHR, 0, stream>>>(Whr, Whz, Whn, bhn, xs, ve, cb, s0, s1);
    finalize<<<8, 256, 0, stream>>>(s0, (float*)d_out);
}

// Round 3
// 2677.552 us; speedup vs baseline: 1.3185x; 1.3185x over previous
//
#include <hip/hip_runtime.h>

#define HDIM 2048
#define TSTEPS 1024
#define NBLK 256
#define NTHR 512

typedef unsigned long long ull;

__device__ __forceinline__ int snake_src(int t) {
    int y = t >> 5, p = t & 31;
    return (y & 1) ? (y * 32 + 31 - p) : t;
}
__device__ __forceinline__ float sigmoid_f(float v) {
    return __builtin_amdgcn_rcpf(1.f + __expf(-v));
}
__device__ __forceinline__ float tanh_f(float v) {
    // 1 - 2/(e^{2v}+1); saturates correctly at +/-inf
    return 1.f - 2.f * __builtin_amdgcn_rcpf(__expf(2.f * v) + 1.f);
}

// ---------------------------------------------------------------------------
// Single persistent kernel. 256 blocks (1/CU) x 512 threads (2 waves/SIMD).
// Thread (c = tid&7, r = tid>>3): column col = blk*8+c, rows [r*32, r*32+32).
// 96 weight floats per thread held in VGPRs (~150 total => no spill at
// launch_bounds(512,2), cap 256/wave).
// Step 0 is fully local (h_0 = 0). Slot buffers need NO init: packed
// {tag,f32} 8B slots; 0xAA poison tag is negative and never matches t.
// ---------------------------------------------------------------------------
__global__ __launch_bounds__(NTHR, 2) void gru_all(
    const float* __restrict__ x,
    const float* __restrict__ We,  const float* __restrict__ be,
    const float* __restrict__ Wir, const float* __restrict__ bir,
    const float* __restrict__ Wiz, const float* __restrict__ biz,
    const float* __restrict__ Win, const float* __restrict__ bin_,
    const float* __restrict__ Whr, const float* __restrict__ Whz,
    const float* __restrict__ Whn, const float* __restrict__ bhn,
    float* __restrict__ out, ull* __restrict__ s0, ull* __restrict__ s1)
{
    const int tid  = threadIdx.x;
    const int blk  = blockIdx.x;
    const int c    = tid & 7;
    const int r    = tid >> 3;            // 0..63
    const int col  = blk * 8 + c;
    const int row0 = r * 32;
    const int lane = tid & 63, wv = tid >> 6;

    __shared__ __align__(16) float lds_h[2304];   // padded: i -> i + ((i>>5)<<2)
    __shared__ float sBe[HDIM];
    __shared__ float red[8][6][8];

    // ---- stage We/be (lds_h temporarily holds We) ----
    for (int i = tid; i < HDIM; i += NTHR) { lds_h[i] = We[i]; sBe[i] = be[i]; }
    __syncthreads();

    // ---- recurrent weights into registers (one-time, stays resident) ----
    float wr[32], wz[32], wn[32];
#pragma unroll
    for (int k = 0; k < 32; ++k) {
        size_t off = (size_t)(row0 + k) * HDIM + col;
        wr[k] = Whr[off];
        wz[k] = Whz[off];
        wn[k] = Whn[off];
    }

    // ---- rank-1 input-path constants for this block's 8 columns ----
    float eR=0,eZ=0,eN=0,bRa=0,bZa=0,bNa=0;
#pragma unroll 8
    for (int k = 0; k < 32; ++k) {
        size_t off = (size_t)(row0 + k) * HDIM + col;
        float we = lds_h[row0 + k], bb = sBe[row0 + k];
        float w0 = Wir[off], w1 = Wiz[off], w2 = Win[off];
        eR  = fmaf(we, w0, eR);  bRa = fmaf(bb, w0, bRa);
        eZ  = fmaf(we, w1, eZ);  bZa = fmaf(bb, w1, bZa);
        eN  = fmaf(we, w2, eN);  bNa = fmaf(bb, w2, bNa);
    }
#pragma unroll
    for (int m = 8; m < 64; m <<= 1) {
        eR  += __shfl_xor(eR,  m, 64); eZ  += __shfl_xor(eZ,  m, 64);
        eN  += __shfl_xor(eN,  m, 64); bRa += __shfl_xor(bRa, m, 64);
        bZa += __shfl_xor(bZa, m, 64); bNa += __shfl_xor(bNa, m, 64);
    }
    if (lane < 8) {
        red[wv][0][lane]=eR;  red[wv][1][lane]=eZ;  red[wv][2][lane]=eN;
        red[wv][3][lane]=bRa; red[wv][4][lane]=bZa; red[wv][5][lane]=bNa;
    }
    __syncthreads();   // also fences lds_h(We)/sBe reads before lds_h reuse

    float vrc=0,vzc=0,vnc=0,crc=0,czc=0,cnc=0,bhc=0;
    if (tid < 8) {
#pragma unroll
        for (int w = 0; w < 8; ++w) {
            vrc += red[w][0][tid]; vzc += red[w][1][tid]; vnc += red[w][2][tid];
            crc += red[w][3][tid]; czc += red[w][4][tid]; cnc += red[w][5][tid];
        }
        crc += bir[col]; czc += biz[col]; cnc += bin_[col];
        bhc = bhn[col];

        // ---- step 0: h_0 == 0, fully local; publish h_1 with tag 1 ----
        float x0 = x[snake_src(0)];
        float ar = fmaf(x0, vrc, crc);
        float az = fmaf(x0, vzc, czc);
        float an = fmaf(x0, vnc, cnc);
        float rg = sigmoid_f(ar), zg = sigmoid_f(az);
        float ng = tanh_f(fmaf(rg, bhc, an));
        float h1 = (1.f - zg) * ng;
        ull pkt = (1ULL << 32) | (ull)__float_as_uint(h1);
        __hip_atomic_store(&s1[col], pkt, __ATOMIC_RELAXED, __HIP_MEMORY_SCOPE_AGENT);
    }

    const int sbase = tid * 4;                      // this thread's 4 h slots
    const int lwb   = sbase + ((sbase >> 5) << 2);  // padded LDS write base (16B aligned)
    const int lrb   = row0  + ((row0  >> 5) << 2);  // padded LDS read base = r*36

    for (int t = 1; t < TSTEPS; ++t) {
        ull* sin  = (t & 1) ? s1 : s0;
        ull* sout = (t & 1) ? s0 : s1;

        // ---- poll tagged slots (data rides inside the 8B atomic) ----
        ull v0, v1, v2, v3;
        for (;;) {
            v0 = __hip_atomic_load(&sin[sbase+0], __ATOMIC_RELAXED, __HIP_MEMORY_SCOPE_AGENT);
            v1 = __hip_atomic_load(&sin[sbase+1], __ATOMIC_RELAXED, __HIP_MEMORY_SCOPE_AGENT);
            v2 = __hip_atomic_load(&sin[sbase+2], __ATOMIC_RELAXED, __HIP_MEMORY_SCOPE_AGENT);
            v3 = __hip_atomic_load(&sin[sbase+3], __ATOMIC_RELAXED, __HIP_MEMORY_SCOPE_AGENT);
            if ((int)(v0 >> 32) == t && (int)(v1 >> 32) == t &&
                (int)(v2 >> 32) == t && (int)(v3 >> 32) == t) break;
        }
        float4 hq = make_float4(__uint_as_float((unsigned)v0), __uint_as_float((unsigned)v1),
                                __uint_as_float((unsigned)v2), __uint_as_float((unsigned)v3));
        *(float4*)&lds_h[lwb] = hq;
        __syncthreads();

        // ---- 96 register-resident FMAs ----
        float a0 = 0.f, a1 = 0.f, a2 = 0.f;
#pragma unroll
        for (int k = 0; k < 32; ++k) {
            float hv = lds_h[lrb + k];
            a0 = fmaf(hv, wr[k], a0);
            a1 = fmaf(hv, wz[k], a1);
            a2 = fmaf(hv, wn[k], a2);
        }
#pragma unroll
        for (int m = 8; m < 64; m <<= 1) {
            a0 += __shfl_xor(a0, m, 64);
            a1 += __shfl_xor(a1, m, 64);
            a2 += __shfl_xor(a2, m, 64);
        }
        if (lane < 8) { red[wv][0][lane]=a0; red[wv][1][lane]=a1; red[wv][2][lane]=a2; }
        __syncthreads();

        // ---- finalize 8 columns ----
        if (tid < 8) {
            float Sr=0, Sz=0, Sn=0;
#pragma unroll
            for (int w = 0; w < 8; ++w) {
                Sr += red[w][0][tid]; Sz += red[w][1][tid]; Sn += red[w][2][tid];
            }
            float xt = x[snake_src(t)];
            float ar = fmaf(xt, vrc, crc) + Sr;
            float az = fmaf(xt, vzc, czc) + Sz;
            float an = fmaf(xt, vnc, cnc);
            float rg = sigmoid_f(ar), zg = sigmoid_f(az);
            float ng = tanh_f(an + rg * (Sn + bhc));
            float hold = lds_h[col + ((col >> 5) << 2)];
            float hnew = (1.f - zg) * ng + zg * hold;
            if (t == TSTEPS - 1) {
                out[col] = hnew;                       // last step -> output
            } else {
                ull pkt = ((ull)(unsigned)(t + 1) << 32) | (ull)__float_as_uint(hnew);
                __hip_atomic_store(&sout[col], pkt, __ATOMIC_RELAXED, __HIP_MEMORY_SCOPE_AGENT);
            }
        }
        __syncthreads();   // protect lds_h/red before next iteration's staging
    }
}

extern "C" void kernel_launch(void* const* d_in, const int* in_sizes, int n_in,
                              void* d_out, int out_size, void* d_ws, size_t ws_size,
                              hipStream_t stream) {
    const float* x    = (const float*)d_in[0];
    const float* We   = (const float*)d_in[1];
    const float* be   = (const float*)d_in[2];
    const float* Wir  = (const float*)d_in[3];
    const float* bir  = (const float*)d_in[4];
    const float* Wiz  = (const float*)d_in[5];
    const float* biz  = (const float*)d_in[6];
    const float* Win  = (const float*)d_in[7];
    const float* bin_ = (const float*)d_in[8];
    const float* Whr  = (const float*)d_in[9];
    const float* Whz  = (const float*)d_in[10];
    const float* Whn  = (const float*)d_in[11];
    const float* bhn  = (const float*)d_in[12];

    ull* s0 = (ull*)d_ws;          // 2048 slots, no init needed (tag protocol)
    ull* s1 = s0 + HDIM;

    gru_all<<<NBLK, NTHR, 0, stream>>>(x, We, be, Wir, bir, Wiz, biz, Win, bin_,
                                       Whr, Whz, Whn, bhn,
                                       (float*)d_out, s0, s1);
}